// Round 16
// baseline (32.341 us; speedup 1.0000x reference)
//
#include <hip/hip_runtime.h>

namespace {

constexpr float kDT = 1e-3f;
constexpr int kB = 512;
constexpr int kT = 8192;
constexpr int kThreads = 1024;
constexpr int kWaves = kThreads / 64;     // 16
constexpr int kPassSteps = 2 * kThreads;  // 2048 steps per pass
constexpr int kPasses = kT / kPassSteps;  // 4

// Affine transform x' = M x + b packed {a,b,c,d,p,q}
struct Xf { float a, b, c, d, p, q; };

__device__ __forceinline__ Xf comp(const Xf& e, const Xf& l) {
  Xf o;
  o.a = l.a * e.a + l.b * e.c;
  o.b = l.a * e.b + l.b * e.d;
  o.c = l.c * e.a + l.d * e.c;
  o.d = l.c * e.b + l.d * e.d;
  o.p = l.a * e.p + l.b * e.q + l.p;
  o.q = l.c * e.p + l.d * e.q + l.q;
  return o;
}

template <int Ctrl, int RowMask>
__device__ __forceinline__ float dpp1(float v, float old) {
  return __int_as_float(__builtin_amdgcn_update_dpp(
      __float_as_int(old), __float_as_int(v), Ctrl, RowMask, 0xf, false));
}

template <int Ctrl, int RowMask>
__device__ __forceinline__ Xf dpp_xf(const Xf& v) {
  Xf r;
  r.a = dpp1<Ctrl, RowMask>(v.a, 1.0f);
  r.b = dpp1<Ctrl, RowMask>(v.b, 0.0f);
  r.c = dpp1<Ctrl, RowMask>(v.c, 0.0f);
  r.d = dpp1<Ctrl, RowMask>(v.d, 1.0f);
  r.p = dpp1<Ctrl, RowMask>(v.p, 0.0f);
  r.q = dpp1<Ctrl, RowMask>(v.q, 0.0f);
  return r;
}

__device__ __forceinline__ Xf wave_incl_scan(Xf x) {
  x = comp(dpp_xf<0x111, 0xf>(x), x);  // row_shr:1
  x = comp(dpp_xf<0x112, 0xf>(x), x);  // row_shr:2
  x = comp(dpp_xf<0x114, 0xf>(x), x);  // row_shr:4
  x = comp(dpp_xf<0x118, 0xf>(x), x);  // row_shr:8
  x = comp(dpp_xf<0x142, 0xa>(x), x);  // row_bcast:15 -> rows 1,3
  x = comp(dpp_xf<0x143, 0xc>(x), x);  // row_bcast:31 -> rows 2,3
  return x;
}

__device__ __forceinline__ Xf readlane_xf(const Xf& v, int l) {
  Xf r;
  r.a = __int_as_float(__builtin_amdgcn_readlane(__float_as_int(v.a), l));
  r.b = __int_as_float(__builtin_amdgcn_readlane(__float_as_int(v.b), l));
  r.c = __int_as_float(__builtin_amdgcn_readlane(__float_as_int(v.c), l));
  r.d = __int_as_float(__builtin_amdgcn_readlane(__float_as_int(v.d), l));
  r.p = __int_as_float(__builtin_amdgcn_readlane(__float_as_int(v.p), l));
  r.q = __int_as_float(__builtin_amdgcn_readlane(__float_as_int(v.q), l));
  return r;
}

__device__ __forceinline__ Xf make_xf(const float4 xv, float d0, float d1,
                                      float A00, float A01, float A10, float A11,
                                      float C00, float C01, float C10, float C11) {
  Xf m;
  m.a = 1.0f + kDT * (A00 - (xv.x * C00 + xv.y * C10));
  m.b =        kDT * (A01 - (xv.x * C01 + xv.y * C11));
  m.c =        kDT * (A10 - (xv.z * C00 + xv.w * C10));
  m.d = 1.0f + kDT * (A11 - (xv.z * C01 + xv.w * C11));
  m.p = xv.x * d0 + xv.y * d1;
  m.q = xv.z * d0 + xv.w * d1;
  return m;
}

// XOR swizzle on float4 index: flips bit0 by bit3. Involution; stays within
// the 128B line; spreads ds_read_b128 of idx {2t,2t+1} over all 8 bank-quads.
__device__ __forceinline__ int swz(int i) { return i ^ ((i >> 3) & 1); }

// Async global->LDS 16B (direct DMA, no VGPR round trip).
__device__ __forceinline__ void gload_lds16(const float4* g, float4* l) {
  __builtin_amdgcn_global_load_lds(
      (const __attribute__((address_space(1))) void*)g,
      (__attribute__((address_space(3))) void*)l, 16, 0, 0);
}

// R12 structure (one block per row, 4 passes, 2 consecutive steps/thread,
// DPP scans, 1 barrier/pass) + xic staged via double-buffered global_load_lds
// with XOR-swizzled source and reads (both-sides swizzle, rule #21).
// R16 fix: prologue barrier drains tile-0 DMA before the first LDS read.
__global__ __launch_bounds__(kThreads) void k_fused(
    const float* __restrict__ xic, const float* __restrict__ dy,
    const float* __restrict__ Ap, const float* __restrict__ Cp,
    float* __restrict__ out) {
  __shared__ float4 sX[2][kPassSteps];     // 2 x 32 KiB xic tiles
  __shared__ float sWT[2][kWaves][6];

  const int tid = threadIdx.x;
  const int lane = tid & 63;
  const int w = tid >> 6;
  const size_t rbase = (size_t)blockIdx.x * kT;        // xic float4 index
  const size_t rbase2 = (size_t)blockIdx.x * (kT / 2); // dy/out float4 index

  const float4* X4 = reinterpret_cast<const float4*>(xic);
  const float4* D4 = reinterpret_cast<const float4*>(dy);
  float4* O4 = reinterpret_cast<float4*>(out);

  const float A00 = Ap[0], A01 = Ap[1], A10 = Ap[2], A11 = Ap[3];
  const float C00 = Cp[0], C01 = Cp[1], C10 = Cp[2], C11 = Cp[3];

  float4 dva[2];

  // Prologue: stage pass 0 xic tile (source pre-swizzled), prefetch dy 0.
  {
    const int d0 = tid, d1 = kThreads + tid;
    gload_lds16(&X4[rbase + swz(d0)], &sX[0][d0]);
    gload_lds16(&X4[rbase + swz(d1)], &sX[0][d1]);
    dva[0] = D4[rbase2 + tid];
  }
  // Drain tile-0 DMA before the first LDS read (missing in R15 -> garbage).
  __syncthreads();

  float x0 = 1.0f, x1 = 0.0f;  // row state entering current pass

#pragma unroll
  for (int c = 0; c < kPasses; ++c) {
    const int buf = c & 1;
    // Stage next pass (async; lands during this pass's compute, made
    // visible by this pass's __syncthreads vmcnt drain).
    if (c + 1 < kPasses) {
      const size_t pb = (size_t)(c + 1) * kPassSteps;
      const int d0 = tid, d1 = kThreads + tid;
      gload_lds16(&X4[rbase + pb + swz(d0)], &sX[buf ^ 1][d0]);
      gload_lds16(&X4[rbase + pb + swz(d1)], &sX[buf ^ 1][d1]);
      dva[buf ^ 1] = D4[rbase2 + (size_t)(c + 1) * kThreads + tid];
    }

    // This pass's xic from LDS (swizzled reads, conflict-free); tile c was
    // drained by the previous barrier (prologue barrier for c==0).
    const float4 xa = sX[buf][swz(2 * tid)];
    const float4 xb = sX[buf][swz(2 * tid + 1)];

    const Xf s0 = make_xf(xa, dva[buf].x, dva[buf].y,
                          A00, A01, A10, A11, C00, C01, C10, C11);
    const Xf s1 = make_xf(xb, dva[buf].z, dva[buf].w,
                          A00, A01, A10, A11, C00, C01, C10, C11);
    const Xf tot = comp(s0, s1);

    // Wave-level inclusive scan (pure VALU/DPP).
    const Xf inc = wave_incl_scan(tot);

    if (lane == 63) {
      sWT[buf][w][0] = inc.a; sWT[buf][w][1] = inc.b; sWT[buf][w][2] = inc.c;
      sWT[buf][w][3] = inc.d; sWT[buf][w][4] = inc.p; sWT[buf][w][5] = inc.q;
    }
    // One barrier per pass: publishes sWT AND drains the next tile's DMA
    // (implicit s_waitcnt vmcnt(0) lgkmcnt(0) before s_barrier).
    __syncthreads();

    // Every wave: lanes 0..15 read the 16 wave totals, 4-round DPP scan.
    Xf v{1.f, 0.f, 0.f, 1.f, 0.f, 0.f};
    if (lane < kWaves) {
      v = Xf{sWT[buf][lane][0], sWT[buf][lane][1], sWT[buf][lane][2],
             sWT[buf][lane][3], sWT[buf][lane][4], sWT[buf][lane][5]};
    }
    v = comp(dpp_xf<0x111, 0xf>(v), v);
    v = comp(dpp_xf<0x112, 0xf>(v), v);
    v = comp(dpp_xf<0x114, 0xf>(v), v);
    v = comp(dpp_xf<0x118, 0xf>(v), v);

    const Xf TT = readlane_xf(v, kWaves - 1);           // pass total
    Xf Ew{1.f, 0.f, 0.f, 1.f, 0.f, 0.f};
    if (w > 0) Ew = readlane_xf(v, w - 1);              // wave-uniform branch

    // Lane-exclusive prefix: whole-wave shift right by 1 (WF_SR1).
    const Xf le = dpp_xf<0x138, 0xf>(inc);              // lane0 -> identity

    const Xf ex = comp(Ew, le);  // block-exclusive prefix for this thread

    const float e0 = ex.a * x0 + ex.b * x1 + ex.p;
    const float e1 = ex.c * x0 + ex.d * x1 + ex.q;

    float4 o;
    o.x = kDT * (C00 * e0 + C01 * e1);
    o.y = kDT * (C10 * e0 + C11 * e1);
    const float t0 = s0.a * e0 + s0.b * e1 + s0.p;
    const float t1 = s0.c * e0 + s0.d * e1 + s0.q;
    o.z = kDT * (C00 * t0 + C01 * t1);
    o.w = kDT * (C10 * t0 + C11 * t1);
    O4[rbase2 + (size_t)c * kThreads + tid] = o;

    if (c + 1 < kPasses) {
      const float n0 = TT.a * x0 + TT.b * x1 + TT.p;
      const float n1 = TT.c * x0 + TT.d * x1 + TT.q;
      x0 = n0; x1 = n1;
    }
  }
}

}  // namespace

extern "C" void kernel_launch(void* const* d_in, const int* in_sizes, int n_in,
                              void* d_out, int out_size, void* d_ws,
                              size_t ws_size, hipStream_t stream) {
  const float* xic = (const float*)d_in[0];  // [B,T,2,2]
  const float* dy  = (const float*)d_in[1];  // [B,T,2]
  const float* Ap  = (const float*)d_in[2];  // [2,2] coeffs_A
  const float* Cp  = (const float*)d_in[3];  // [2,2] C
  float* out = (float*)d_out;                // [B,T,2]

  k_fused<<<kB, kThreads, 0, stream>>>(xic, dy, Ap, Cp, out);
}